// Round 1
// baseline (1084.092 us; speedup 1.0000x reference)
//
#include <hip/hip_runtime.h>
#include <math.h>

// Problem constants (from setup_inputs)
#define T_TOK 2048   // B*S
#define D_DIM 1024   // hidden
#define E_NUM 8      // experts
#define DFS   2048   // shared ffn
#define DFE   512    // expert ffn

// ---------------------------------------------------------------------------
// Kernel 1: router. One 64-lane wave per token.
// lane = chunk*8 + expert ; each lane dots 128 elements, reduce over chunks.
// ---------------------------------------------------------------------------
__global__ __launch_bounds__(64) void router_kernel(
    const float* __restrict__ x, const float* __restrict__ rw,
    const float* __restrict__ alpha,
    int* __restrict__ cnt, int* __restrict__ tok_list,
    float* __restrict__ tok_coef, float* __restrict__ csum) {
  const int t = blockIdx.x;
  const int lane = threadIdx.x;
  const int e = lane & 7;
  const int chunk = lane >> 3;  // 0..7
  const float* xr = x + (size_t)t * D_DIM + chunk * 128;
  const float* wr = rw + (size_t)e * D_DIM + chunk * 128;
  float acc = 0.f;
#pragma unroll 8
  for (int j = 0; j < 128; ++j) acc += xr[j] * wr[j];
  // reduce over chunk dimension (lane bits 3..5)
  acc += __shfl_xor(acc, 8);
  acc += __shfl_xor(acc, 16);
  acc += __shfl_xor(acc, 32);
  __shared__ float logits[E_NUM];
  if (lane < 8) logits[e] = acc;
  __syncthreads();
  if (lane == 0) {
    int i0 = 0; float v0 = logits[0];
#pragma unroll
    for (int i = 1; i < E_NUM; ++i) if (logits[i] > v0) { v0 = logits[i]; i0 = i; }
    int i1 = -1; float v1 = -1e30f;
#pragma unroll
    for (int i = 0; i < E_NUM; ++i) {
      if (i == i0) continue;
      if (logits[i] > v1) { v1 = logits[i]; i1 = i; }
    }
    float w0 = 1.f / (1.f + __expf(v1 - v0));
    float w1 = 1.f - w0;
    float c0 = w0 * alpha[i0];
    float c1 = w1 * alpha[i1];
    csum[t] = c0 + c1;
    int p0 = atomicAdd(&cnt[i0], 1);
    tok_list[i0 * T_TOK + p0] = t; tok_coef[i0 * T_TOK + p0] = c0;
    int p1 = atomicAdd(&cnt[i1], 1);
    tok_list[i1 * T_TOK + p1] = t; tok_coef[i1 * T_TOK + p1] = c1;
  }
}

// ---------------------------------------------------------------------------
// Kernel 2: shared gate+up fused GEMM.  s = silu(x@Wg^T) * (x@Wu^T)  [T, DFS]
// 64x64 tile, 256 threads, 4x4 per thread, K-tile 16.
// ---------------------------------------------------------------------------
__global__ __launch_bounds__(256) void shared_gateup_kernel(
    const float* __restrict__ x, const float* __restrict__ wg,
    const float* __restrict__ wu, float* __restrict__ sbuf) {
  __shared__ float As[16][65];
  __shared__ float Bg[16][65];
  __shared__ float Bu[16][65];
  const int tid = threadIdx.x;
  const int tx = tid & 15, ty = tid >> 4;
  const int m0 = blockIdx.y * 64, n0 = blockIdx.x * 64;
  const int lm = tid >> 2;          // 0..63
  const int lk = (tid & 3) * 4;     // 0,4,8,12
  float cg[4][4] = {}, cu[4][4] = {};
  for (int k0 = 0; k0 < D_DIM; k0 += 16) {
    const float4 av = *(const float4*)(x  + (size_t)(m0 + lm) * D_DIM + k0 + lk);
    const float4 gv = *(const float4*)(wg + (size_t)(n0 + lm) * D_DIM + k0 + lk);
    const float4 uv = *(const float4*)(wu + (size_t)(n0 + lm) * D_DIM + k0 + lk);
    __syncthreads();
    As[lk+0][lm] = av.x; As[lk+1][lm] = av.y; As[lk+2][lm] = av.z; As[lk+3][lm] = av.w;
    Bg[lk+0][lm] = gv.x; Bg[lk+1][lm] = gv.y; Bg[lk+2][lm] = gv.z; Bg[lk+3][lm] = gv.w;
    Bu[lk+0][lm] = uv.x; Bu[lk+1][lm] = uv.y; Bu[lk+2][lm] = uv.z; Bu[lk+3][lm] = uv.w;
    __syncthreads();
#pragma unroll
    for (int k = 0; k < 16; ++k) {
      float a[4], bg[4], bu[4];
#pragma unroll
      for (int i = 0; i < 4; ++i) a[i] = As[k][ty * 4 + i];
#pragma unroll
      for (int j = 0; j < 4; ++j) { bg[j] = Bg[k][tx * 4 + j]; bu[j] = Bu[k][tx * 4 + j]; }
#pragma unroll
      for (int i = 0; i < 4; ++i)
#pragma unroll
        for (int j = 0; j < 4; ++j) {
          cg[i][j] = fmaf(a[i], bg[j], cg[i][j]);
          cu[i][j] = fmaf(a[i], bu[j], cu[i][j]);
        }
    }
  }
#pragma unroll
  for (int i = 0; i < 4; ++i) {
    const size_t row = (size_t)(m0 + ty * 4 + i) * DFS;
#pragma unroll
    for (int j = 0; j < 4; ++j) {
      float g = cg[i][j], u = cu[i][j];
      float s = (g / (1.f + __expf(-g))) * u;  // silu(g)*u
      sbuf[row + n0 + tx * 4 + j] = s;
    }
  }
}

// ---------------------------------------------------------------------------
// Kernel 3: shared down GEMM.  out[t,d] = (1 - csum[t]) * (s @ Wd^T)[t,d]
// ---------------------------------------------------------------------------
__global__ __launch_bounds__(256) void shared_down_kernel(
    const float* __restrict__ sbuf, const float* __restrict__ wd,
    const float* __restrict__ csum, float* __restrict__ out) {
  __shared__ float As[16][65];
  __shared__ float Bs[16][65];
  const int tid = threadIdx.x;
  const int tx = tid & 15, ty = tid >> 4;
  const int m0 = blockIdx.y * 64, n0 = blockIdx.x * 64;
  const int lm = tid >> 2;
  const int lk = (tid & 3) * 4;
  float c[4][4] = {};
  for (int k0 = 0; k0 < DFS; k0 += 16) {
    const float4 av = *(const float4*)(sbuf + (size_t)(m0 + lm) * DFS + k0 + lk);
    const float4 bv = *(const float4*)(wd   + (size_t)(n0 + lm) * DFS + k0 + lk);
    __syncthreads();
    As[lk+0][lm] = av.x; As[lk+1][lm] = av.y; As[lk+2][lm] = av.z; As[lk+3][lm] = av.w;
    Bs[lk+0][lm] = bv.x; Bs[lk+1][lm] = bv.y; Bs[lk+2][lm] = bv.z; Bs[lk+3][lm] = bv.w;
    __syncthreads();
#pragma unroll
    for (int k = 0; k < 16; ++k) {
      float a[4], b[4];
#pragma unroll
      for (int i = 0; i < 4; ++i) a[i] = As[k][ty * 4 + i];
#pragma unroll
      for (int j = 0; j < 4; ++j) b[j] = Bs[k][tx * 4 + j];
#pragma unroll
      for (int i = 0; i < 4; ++i)
#pragma unroll
        for (int j = 0; j < 4; ++j) c[i][j] = fmaf(a[i], b[j], c[i][j]);
    }
  }
#pragma unroll
  for (int i = 0; i < 4; ++i) {
    const int m = m0 + ty * 4 + i;
    const float scale = 1.f - csum[m];
#pragma unroll
    for (int j = 0; j < 4; ++j)
      out[(size_t)m * D_DIM + n0 + tx * 4 + j] = scale * c[i][j];
  }
}

// ---------------------------------------------------------------------------
// Kernel 4: expert gate+up GEMM over gathered token lists, int-dequant B.
// act[e, slot, f] = silu(g)*u  with per-f scales applied in epilogue.
// grid: (DFE/64, T/64, E)
// ---------------------------------------------------------------------------
__global__ __launch_bounds__(256) void expert_gateup_kernel(
    const float* __restrict__ x, const int* __restrict__ gate_q,
    const int* __restrict__ up_q, const float* __restrict__ gate_s,
    const float* __restrict__ up_s, const int* __restrict__ cnt,
    const int* __restrict__ tok_list, float* __restrict__ act_buf) {
  const int e = blockIdx.z;
  const int ce = cnt[e];
  const int m0 = blockIdx.y * 64;
  if (m0 >= ce) return;
  const int n0 = blockIdx.x * 64;
  __shared__ float As[16][65];
  __shared__ float Bg[16][65];
  __shared__ float Bu[16][65];
  const int tid = threadIdx.x;
  const int tx = tid & 15, ty = tid >> 4;
  const int lm = tid >> 2;
  const int lk = (tid & 3) * 4;
  const int mm_l = m0 + lm;
  const int tok = (mm_l < ce) ? tok_list[e * T_TOK + mm_l] : 0;  // dummy row 0 if OOB
  const int* gq = gate_q + (size_t)e * DFE * D_DIM;
  const int* uq = up_q   + (size_t)e * DFE * D_DIM;
  float cg[4][4] = {}, cu[4][4] = {};
  for (int k0 = 0; k0 < D_DIM; k0 += 16) {
    const float4 av = *(const float4*)(x + (size_t)tok * D_DIM + k0 + lk);
    const int4 gv = *(const int4*)(gq + (size_t)(n0 + lm) * D_DIM + k0 + lk);
    const int4 uv = *(const int4*)(uq + (size_t)(n0 + lm) * D_DIM + k0 + lk);
    __syncthreads();
    As[lk+0][lm] = av.x; As[lk+1][lm] = av.y; As[lk+2][lm] = av.z; As[lk+3][lm] = av.w;
    Bg[lk+0][lm] = (float)gv.x; Bg[lk+1][lm] = (float)gv.y; Bg[lk+2][lm] = (float)gv.z; Bg[lk+3][lm] = (float)gv.w;
    Bu[lk+0][lm] = (float)uv.x; Bu[lk+1][lm] = (float)uv.y; Bu[lk+2][lm] = (float)uv.z; Bu[lk+3][lm] = (float)uv.w;
    __syncthreads();
#pragma unroll
    for (int k = 0; k < 16; ++k) {
      float a[4], bg[4], bu[4];
#pragma unroll
      for (int i = 0; i < 4; ++i) a[i] = As[k][ty * 4 + i];
#pragma unroll
      for (int j = 0; j < 4; ++j) { bg[j] = Bg[k][tx * 4 + j]; bu[j] = Bu[k][tx * 4 + j]; }
#pragma unroll
      for (int i = 0; i < 4; ++i)
#pragma unroll
        for (int j = 0; j < 4; ++j) {
          cg[i][j] = fmaf(a[i], bg[j], cg[i][j]);
          cu[i][j] = fmaf(a[i], bu[j], cu[i][j]);
        }
    }
  }
#pragma unroll
  for (int i = 0; i < 4; ++i) {
    const int mm = m0 + ty * 4 + i;
    if (mm >= ce) continue;
    const size_t row = ((size_t)e * T_TOK + mm) * DFE;
#pragma unroll
    for (int j = 0; j < 4; ++j) {
      const int f = n0 + tx * 4 + j;
      float g = cg[i][j] * gate_s[e * DFE + f];
      float u = cu[i][j] * up_s[e * DFE + f];
      act_buf[row + f] = (g / (1.f + __expf(-g))) * u;
    }
  }
}

// ---------------------------------------------------------------------------
// Kernel 5: expert down GEMM, epilogue atomicAdd(out, coef * eo).
// grid: (D/64, T/64, E)
// ---------------------------------------------------------------------------
__global__ __launch_bounds__(256) void expert_down_kernel(
    const float* __restrict__ act_buf, const int* __restrict__ down_q,
    const float* __restrict__ down_s, const int* __restrict__ cnt,
    const int* __restrict__ tok_list, const float* __restrict__ tok_coef,
    float* __restrict__ out) {
  const int e = blockIdx.z;
  const int ce = cnt[e];
  const int m0 = blockIdx.y * 64;
  if (m0 >= ce) return;
  const int n0 = blockIdx.x * 64;
  __shared__ float As[16][65];
  __shared__ float Bs[16][65];
  const int tid = threadIdx.x;
  const int tx = tid & 15, ty = tid >> 4;
  const int lm = tid >> 2;
  const int lk = (tid & 3) * 4;
  const float* act = act_buf + (size_t)e * T_TOK * DFE;
  const int* dq = down_q + (size_t)e * D_DIM * DFE;
  float c[4][4] = {};
  for (int k0 = 0; k0 < DFE; k0 += 16) {
    const float4 av = *(const float4*)(act + (size_t)(m0 + lm) * DFE + k0 + lk);
    const int4 bv = *(const int4*)(dq + (size_t)(n0 + lm) * DFE + k0 + lk);
    __syncthreads();
    As[lk+0][lm] = av.x; As[lk+1][lm] = av.y; As[lk+2][lm] = av.z; As[lk+3][lm] = av.w;
    Bs[lk+0][lm] = (float)bv.x; Bs[lk+1][lm] = (float)bv.y; Bs[lk+2][lm] = (float)bv.z; Bs[lk+3][lm] = (float)bv.w;
    __syncthreads();
#pragma unroll
    for (int k = 0; k < 16; ++k) {
      float a[4], b[4];
#pragma unroll
      for (int i = 0; i < 4; ++i) a[i] = As[k][ty * 4 + i];
#pragma unroll
      for (int j = 0; j < 4; ++j) b[j] = Bs[k][tx * 4 + j];
#pragma unroll
      for (int i = 0; i < 4; ++i)
#pragma unroll
        for (int j = 0; j < 4; ++j) c[i][j] = fmaf(a[i], b[j], c[i][j]);
    }
  }
#pragma unroll
  for (int i = 0; i < 4; ++i) {
    const int mm = m0 + ty * 4 + i;
    if (mm >= ce) continue;
    const int t = tok_list[e * T_TOK + mm];
    const float coef = tok_coef[e * T_TOK + mm];
#pragma unroll
    for (int j = 0; j < 4; ++j) {
      const int d = n0 + tx * 4 + j;
      const float val = c[i][j] * down_s[e * D_DIM + d];
      atomicAdd(&out[(size_t)t * D_DIM + d], coef * val);
    }
  }
}

// ---------------------------------------------------------------------------
extern "C" void kernel_launch(void* const* d_in, const int* in_sizes, int n_in,
                              void* d_out, int out_size, void* d_ws, size_t ws_size,
                              hipStream_t stream) {
  const float* x         = (const float*)d_in[0];
  const float* rw        = (const float*)d_in[1];
  const float* sh_gate_w = (const float*)d_in[2];
  const float* sh_up_w   = (const float*)d_in[3];
  const float* sh_down_w = (const float*)d_in[4];
  const float* gate_s    = (const float*)d_in[5];
  const float* up_s      = (const float*)d_in[6];
  const float* down_s    = (const float*)d_in[7];
  const float* alpha     = (const float*)d_in[8];
  const int*   gate_q    = (const int*)d_in[9];
  const int*   up_q      = (const int*)d_in[10];
  const int*   down_q    = (const int*)d_in[11];
  // d_in[12] = top_k (known = 2)

  char* ws = (char*)d_ws;
  int*   cnt      = (int*)ws;                            // 8 ints
  int*   tok_list = (int*)(ws + 1024);                   // 8*2048 ints
  float* tok_coef = (float*)(ws + 1024 + 65536);         // 8*2048 floats
  float* csum     = (float*)(ws + 1024 + 2 * 65536);     // 2048 floats
  float* sbuf     = (float*)(ws + (1u << 20));                         // 16 MB
  float* act_buf  = (float*)(ws + (1u << 20) + ((size_t)16 << 20));    // 16 MB

  float* out = (float*)d_out;

  hipMemsetAsync(cnt, 0, E_NUM * sizeof(int), stream);
  router_kernel<<<T_TOK, 64, 0, stream>>>(x, rw, alpha, cnt, tok_list, tok_coef, csum);
  shared_gateup_kernel<<<dim3(DFS / 64, T_TOK / 64), 256, 0, stream>>>(x, sh_gate_w, sh_up_w, sbuf);
  shared_down_kernel<<<dim3(D_DIM / 64, T_TOK / 64), 256, 0, stream>>>(sbuf, sh_down_w, csum, out);
  expert_gateup_kernel<<<dim3(DFE / 64, T_TOK / 64, E_NUM), 256, 0, stream>>>(
      x, gate_q, up_q, gate_s, up_s, cnt, tok_list, act_buf);
  expert_down_kernel<<<dim3(D_DIM / 64, T_TOK / 64, E_NUM), 256, 0, stream>>>(
      act_buf, down_q, down_s, cnt, tok_list, tok_coef, out);
}

// Round 2
// 349.296 us; speedup vs baseline: 3.1036x; 3.1036x over previous
//
#include <hip/hip_runtime.h>
#include <math.h>

// Problem constants (from setup_inputs)
#define T_TOK 2048   // B*S
#define D_DIM 1024   // hidden
#define E_NUM 8      // experts
#define DFS   2048   // shared ffn
#define DFE   512    // expert ffn

#define BM 128
#define BN 128
#define BK 32

typedef short short8 __attribute__((ext_vector_type(8)));
typedef float floatx4 __attribute__((ext_vector_type(4)));
typedef unsigned short ushort;

// float -> bf16 (RNE)
__device__ __forceinline__ ushort f2b(float f) {
  union { float f; unsigned u; } v; v.f = f;
  unsigned r = (v.u + 0x7fffu + ((v.u >> 16) & 1u)) >> 16;
  return (ushort)r;
}

// async global->LDS, 16B per lane. lds ptr must be wave-uniform.
__device__ __forceinline__ void gld16(const ushort* g, ushort* l) {
  __builtin_amdgcn_global_load_lds(
      (const __attribute__((address_space(1))) void*)g,
      (__attribute__((address_space(3))) void*)l,
      16, 0, 0);
}

__device__ __forceinline__ float silu_mul(float g, float u) {
  return (g / (1.f + __expf(-g))) * u;
}

// ---------------------------------------------------------------------------
// Conversion: 4x fp32 arrays of 2M elements -> bf16.  grid (1024, 4) x 256.
// ---------------------------------------------------------------------------
__global__ __launch_bounds__(256) void cvt_f32_bf16_multi(
    const float* __restrict__ s0, const float* __restrict__ s1,
    const float* __restrict__ s2, const float* __restrict__ s3,
    ushort* __restrict__ d0, ushort* __restrict__ d1,
    ushort* __restrict__ d2, ushort* __restrict__ d3) {
  const float* src; ushort* dst;
  switch (blockIdx.y) {
    case 0: src = s0; dst = d0; break;
    case 1: src = s1; dst = d1; break;
    case 2: src = s2; dst = d2; break;
    default: src = s3; dst = d3; break;
  }
  size_t i = (size_t)blockIdx.x * 256 + threadIdx.x;   // 8 floats per thread
  const float4* sp = (const float4*)src;
  float4 a = sp[2 * i], b = sp[2 * i + 1];
  union { ushort u[8]; uint4 v; } o;
  o.u[0] = f2b(a.x); o.u[1] = f2b(a.y); o.u[2] = f2b(a.z); o.u[3] = f2b(a.w);
  o.u[4] = f2b(b.x); o.u[5] = f2b(b.y); o.u[6] = f2b(b.z); o.u[7] = f2b(b.w);
  ((uint4*)dst)[i] = o.v;
}

// 3x int32 arrays of 4M elements -> bf16 (exact for |v|<=128). grid (2048,3).
__global__ __launch_bounds__(256) void cvt_i32_bf16_multi(
    const int* __restrict__ s0, const int* __restrict__ s1,
    const int* __restrict__ s2,
    ushort* __restrict__ d0, ushort* __restrict__ d1, ushort* __restrict__ d2) {
  const int* src; ushort* dst;
  switch (blockIdx.y) {
    case 0: src = s0; dst = d0; break;
    case 1: src = s1; dst = d1; break;
    default: src = s2; dst = d2; break;
  }
  size_t i = (size_t)blockIdx.x * 256 + threadIdx.x;
  const int4* sp = (const int4*)src;
  int4 a = sp[2 * i], b = sp[2 * i + 1];
  union { ushort u[8]; uint4 v; } o;
  o.u[0] = f2b((float)a.x); o.u[1] = f2b((float)a.y);
  o.u[2] = f2b((float)a.z); o.u[3] = f2b((float)a.w);
  o.u[4] = f2b((float)b.x); o.u[5] = f2b((float)b.y);
  o.u[6] = f2b((float)b.z); o.u[7] = f2b((float)b.w);
  ((uint4*)dst)[i] = o.v;
}

// ---------------------------------------------------------------------------
// Router: one wave per token; top-2 + softmax; scatter into expert lists.
// ---------------------------------------------------------------------------
__global__ __launch_bounds__(64) void router_kernel(
    const float* __restrict__ x, const float* __restrict__ rw,
    const float* __restrict__ alpha,
    int* __restrict__ cnt, int* __restrict__ tok_list,
    float* __restrict__ tok_coef, float* __restrict__ csum) {
  const int t = blockIdx.x;
  const int lane = threadIdx.x;
  const int e = lane & 7;
  const int chunk = lane >> 3;  // 0..7
  const float* xr = x + (size_t)t * D_DIM + chunk * 128;
  const float* wr = rw + (size_t)e * D_DIM + chunk * 128;
  float acc = 0.f;
#pragma unroll 8
  for (int j = 0; j < 128; ++j) acc += xr[j] * wr[j];
  acc += __shfl_xor(acc, 8);
  acc += __shfl_xor(acc, 16);
  acc += __shfl_xor(acc, 32);
  __shared__ float logits[E_NUM];
  if (lane < 8) logits[e] = acc;
  __syncthreads();
  if (lane == 0) {
    int i0 = 0; float v0 = logits[0];
#pragma unroll
    for (int i = 1; i < E_NUM; ++i) if (logits[i] > v0) { v0 = logits[i]; i0 = i; }
    int i1 = -1; float v1 = -1e30f;
#pragma unroll
    for (int i = 0; i < E_NUM; ++i) {
      if (i == i0) continue;
      if (logits[i] > v1) { v1 = logits[i]; i1 = i; }
    }
    float w0 = 1.f / (1.f + __expf(v1 - v0));
    float w1 = 1.f - w0;
    float c0 = w0 * alpha[i0];
    float c1 = w1 * alpha[i1];
    csum[t] = c0 + c1;
    int p0 = atomicAdd(&cnt[i0], 1);
    tok_list[i0 * T_TOK + p0] = t; tok_coef[i0 * T_TOK + p0] = c0;
    int p1 = atomicAdd(&cnt[i1], 1);
    tok_list[i1 * T_TOK + p1] = t; tok_coef[i1 * T_TOK + p1] = c1;
  }
}

// ---------------------------------------------------------------------------
// MFMA GEMM kernels.  128x128 tile, BK=32, 4 waves, each wave 64x64.
// A [M,K] bf16 row-major; B [N,K] bf16 row-major (i.e. B^T GEMM).
// ---------------------------------------------------------------------------

// Shared gate+up fused:  s = silu(x@Wg^T) * (x@Wu^T), bf16 out [T, DFS]
__global__ __launch_bounds__(256) void mfma_shared_gateup(
    const ushort* __restrict__ xb, const ushort* __restrict__ wg,
    const ushort* __restrict__ wu, ushort* __restrict__ sbuf) {
  __shared__ ushort As[BM * BK];
  __shared__ ushort Bg[BN * BK];
  __shared__ ushort Bu[BN * BK];
  const int tid = threadIdx.x;
  const int wave = tid >> 6, lane = tid & 63;
  const int wr = wave >> 1, wc = wave & 1;
  const int m0 = blockIdx.y * BM, n0 = blockIdx.x * BN;
  const int srow = lane >> 2;           // 0..15
  const int scol = (lane & 3) * 8;      // element offset within 32-elem row
  const int K = D_DIM;

  const ushort* a0 = xb + (size_t)(m0 + wave * 32 + srow) * K + scol;
  const ushort* a1 = a0 + (size_t)16 * K;
  const ushort* g0 = wg + (size_t)(n0 + wave * 32 + srow) * K + scol;
  const ushort* g1 = g0 + (size_t)16 * K;
  const ushort* u0 = wu + (size_t)(n0 + wave * 32 + srow) * K + scol;
  const ushort* u1 = u0 + (size_t)16 * K;
  ushort* lA0 = &As[(wave * 32) * BK];      ushort* lA1 = &As[(wave * 32 + 16) * BK];
  ushort* lG0 = &Bg[(wave * 32) * BK];      ushort* lG1 = &Bg[(wave * 32 + 16) * BK];
  ushort* lU0 = &Bu[(wave * 32) * BK];      ushort* lU1 = &Bu[(wave * 32 + 16) * BK];

  floatx4 accg[4][4], accu[4][4];
#pragma unroll
  for (int i = 0; i < 4; ++i)
#pragma unroll
    for (int j = 0; j < 4; ++j) { accg[i][j] = (floatx4)(0.f); accu[i][j] = (floatx4)(0.f); }

  const int kc = (lane >> 4) * 8;
  const int rb = lane & 15;

  for (int k0 = 0; k0 < K; k0 += BK) {
    gld16(a0 + k0, lA0); gld16(a1 + k0, lA1);
    gld16(g0 + k0, lG0); gld16(g1 + k0, lG1);
    gld16(u0 + k0, lU0); gld16(u1 + k0, lU1);
    __syncthreads();
    short8 af[4], gf[4], uf[4];
#pragma unroll
    for (int mt = 0; mt < 4; ++mt)
      af[mt] = *(const short8*)&As[(wr * 64 + mt * 16 + rb) * BK + kc];
#pragma unroll
    for (int nt = 0; nt < 4; ++nt) {
      gf[nt] = *(const short8*)&Bg[(wc * 64 + nt * 16 + rb) * BK + kc];
      uf[nt] = *(const short8*)&Bu[(wc * 64 + nt * 16 + rb) * BK + kc];
    }
#pragma unroll
    for (int mt = 0; mt < 4; ++mt)
#pragma unroll
      for (int nt = 0; nt < 4; ++nt) {
        accg[mt][nt] = __builtin_amdgcn_mfma_f32_16x16x32_bf16(af[mt], gf[nt], accg[mt][nt], 0, 0, 0);
        accu[mt][nt] = __builtin_amdgcn_mfma_f32_16x16x32_bf16(af[mt], uf[nt], accu[mt][nt], 0, 0, 0);
      }
    __syncthreads();
  }
  // epilogue: silu(g)*u -> bf16
#pragma unroll
  for (int mt = 0; mt < 4; ++mt)
#pragma unroll
    for (int nt = 0; nt < 4; ++nt) {
      const int col = n0 + wc * 64 + nt * 16 + (lane & 15);
#pragma unroll
      for (int r = 0; r < 4; ++r) {
        const int row = m0 + wr * 64 + mt * 16 + (lane >> 4) * 4 + r;
        float s = silu_mul(accg[mt][nt][r], accu[mt][nt][r]);
        sbuf[(size_t)row * DFS + col] = f2b(s);
      }
    }
}

// Shared down:  out[t,d] = (1-csum[t]) * (s @ Wd^T)
__global__ __launch_bounds__(256) void mfma_shared_down(
    const ushort* __restrict__ sb, const ushort* __restrict__ wd,
    const float* __restrict__ csum, float* __restrict__ out) {
  __shared__ ushort As[BM * BK];
  __shared__ ushort Bs[BN * BK];
  const int tid = threadIdx.x;
  const int wave = tid >> 6, lane = tid & 63;
  const int wr = wave >> 1, wc = wave & 1;
  const int m0 = blockIdx.y * BM, n0 = blockIdx.x * BN;
  const int srow = lane >> 2;
  const int scol = (lane & 3) * 8;
  const int K = DFS;

  const ushort* a0 = sb + (size_t)(m0 + wave * 32 + srow) * K + scol;
  const ushort* a1 = a0 + (size_t)16 * K;
  const ushort* b0 = wd + (size_t)(n0 + wave * 32 + srow) * K + scol;
  const ushort* b1 = b0 + (size_t)16 * K;
  ushort* lA0 = &As[(wave * 32) * BK];  ushort* lA1 = &As[(wave * 32 + 16) * BK];
  ushort* lB0 = &Bs[(wave * 32) * BK];  ushort* lB1 = &Bs[(wave * 32 + 16) * BK];

  floatx4 acc[4][4];
#pragma unroll
  for (int i = 0; i < 4; ++i)
#pragma unroll
    for (int j = 0; j < 4; ++j) acc[i][j] = (floatx4)(0.f);

  const int kc = (lane >> 4) * 8;
  const int rb = lane & 15;

  for (int k0 = 0; k0 < K; k0 += BK) {
    gld16(a0 + k0, lA0); gld16(a1 + k0, lA1);
    gld16(b0 + k0, lB0); gld16(b1 + k0, lB1);
    __syncthreads();
    short8 af[4], bf[4];
#pragma unroll
    for (int mt = 0; mt < 4; ++mt)
      af[mt] = *(const short8*)&As[(wr * 64 + mt * 16 + rb) * BK + kc];
#pragma unroll
    for (int nt = 0; nt < 4; ++nt)
      bf[nt] = *(const short8*)&Bs[(wc * 64 + nt * 16 + rb) * BK + kc];
#pragma unroll
    for (int mt = 0; mt < 4; ++mt)
#pragma unroll
      for (int nt = 0; nt < 4; ++nt)
        acc[mt][nt] = __builtin_amdgcn_mfma_f32_16x16x32_bf16(af[mt], bf[nt], acc[mt][nt], 0, 0, 0);
    __syncthreads();
  }
#pragma unroll
  for (int mt = 0; mt < 4; ++mt)
#pragma unroll
    for (int nt = 0; nt < 4; ++nt) {
      const int col = n0 + wc * 64 + nt * 16 + (lane & 15);
#pragma unroll
      for (int r = 0; r < 4; ++r) {
        const int row = m0 + wr * 64 + mt * 16 + (lane >> 4) * 4 + r;
        out[(size_t)row * D_DIM + col] = (1.f - csum[row]) * acc[mt][nt][r];
      }
    }
}

// Expert gate+up (gathered rows):  act[e,slot,f] = silu(g*gs)* (u*us), bf16
__global__ __launch_bounds__(256) void mfma_expert_gateup(
    const ushort* __restrict__ xb, const ushort* __restrict__ gq,
    const ushort* __restrict__ uq, const float* __restrict__ gate_s,
    const float* __restrict__ up_s, const int* __restrict__ cnt,
    const int* __restrict__ tok_list, ushort* __restrict__ act) {
  const int e = blockIdx.z;
  const int ce = cnt[e];
  const int m0 = blockIdx.y * BM;
  if (m0 >= ce) return;
  const int n0 = blockIdx.x * BN;
  __shared__ ushort As[BM * BK];
  __shared__ ushort Bg[BN * BK];
  __shared__ ushort Bu[BN * BK];
  const int tid = threadIdx.x;
  const int wave = tid >> 6, lane = tid & 63;
  const int wr = wave >> 1, wc = wave & 1;
  const int srow = lane >> 2;
  const int scol = (lane & 3) * 8;
  const int K = D_DIM;

  const int r0 = m0 + wave * 32 + srow;
  const int r1 = r0 + 16;
  const int tk0 = (r0 < ce) ? tok_list[e * T_TOK + r0] : 0;
  const int tk1 = (r1 < ce) ? tok_list[e * T_TOK + r1] : 0;
  const ushort* a0 = xb + (size_t)tk0 * K + scol;
  const ushort* a1 = xb + (size_t)tk1 * K + scol;
  const ushort* gqe = gq + (size_t)e * DFE * D_DIM;
  const ushort* uqe = uq + (size_t)e * DFE * D_DIM;
  const ushort* g0 = gqe + (size_t)(n0 + wave * 32 + srow) * K + scol;
  const ushort* g1 = g0 + (size_t)16 * K;
  const ushort* u0 = uqe + (size_t)(n0 + wave * 32 + srow) * K + scol;
  const ushort* u1 = u0 + (size_t)16 * K;
  ushort* lA0 = &As[(wave * 32) * BK];  ushort* lA1 = &As[(wave * 32 + 16) * BK];
  ushort* lG0 = &Bg[(wave * 32) * BK];  ushort* lG1 = &Bg[(wave * 32 + 16) * BK];
  ushort* lU0 = &Bu[(wave * 32) * BK];  ushort* lU1 = &Bu[(wave * 32 + 16) * BK];

  floatx4 accg[4][4], accu[4][4];
#pragma unroll
  for (int i = 0; i < 4; ++i)
#pragma unroll
    for (int j = 0; j < 4; ++j) { accg[i][j] = (floatx4)(0.f); accu[i][j] = (floatx4)(0.f); }

  const int kc = (lane >> 4) * 8;
  const int rb = lane & 15;

  for (int k0 = 0; k0 < K; k0 += BK) {
    gld16(a0 + k0, lA0); gld16(a1 + k0, lA1);
    gld16(g0 + k0, lG0); gld16(g1 + k0, lG1);
    gld16(u0 + k0, lU0); gld16(u1 + k0, lU1);
    __syncthreads();
    short8 af[4], gf[4], uf[4];
#pragma unroll
    for (int mt = 0; mt < 4; ++mt)
      af[mt] = *(const short8*)&As[(wr * 64 + mt * 16 + rb) * BK + kc];
#pragma unroll
    for (int nt = 0; nt < 4; ++nt) {
      gf[nt] = *(const short8*)&Bg[(wc * 64 + nt * 16 + rb) * BK + kc];
      uf[nt] = *(const short8*)&Bu[(wc * 64 + nt * 16 + rb) * BK + kc];
    }
#pragma unroll
    for (int mt = 0; mt < 4; ++mt)
#pragma unroll
      for (int nt = 0; nt < 4; ++nt) {
        accg[mt][nt] = __builtin_amdgcn_mfma_f32_16x16x32_bf16(af[mt], gf[nt], accg[mt][nt], 0, 0, 0);
        accu[mt][nt] = __builtin_amdgcn_mfma_f32_16x16x32_bf16(af[mt], uf[nt], accu[mt][nt], 0, 0, 0);
      }
    __syncthreads();
  }
#pragma unroll
  for (int mt = 0; mt < 4; ++mt)
#pragma unroll
    for (int nt = 0; nt < 4; ++nt) {
      const int col = n0 + wc * 64 + nt * 16 + (lane & 15);
      const float gsc = gate_s[e * DFE + col];
      const float usc = up_s[e * DFE + col];
#pragma unroll
      for (int r = 0; r < 4; ++r) {
        const int slot = m0 + wr * 64 + mt * 16 + (lane >> 4) * 4 + r;
        float s = silu_mul(accg[mt][nt][r] * gsc, accu[mt][nt][r] * usc);
        act[((size_t)e * T_TOK + slot) * DFE + col] = f2b(s);
      }
    }
}

// Expert down:  out[tok,d] += coef * (act @ Wd^T) * down_s[d]   (atomic)
__global__ __launch_bounds__(256) void mfma_expert_down(
    const ushort* __restrict__ act, const ushort* __restrict__ dq,
    const float* __restrict__ down_s, const int* __restrict__ cnt,
    const int* __restrict__ tok_list, const float* __restrict__ tok_coef,
    float* __restrict__ out) {
  const int e = blockIdx.z;
  const int ce = cnt[e];
  const int m0 = blockIdx.y * BM;
  if (m0 >= ce) return;
  const int n0 = blockIdx.x * BN;
  __shared__ ushort As[BM * BK];
  __shared__ ushort Bs[BN * BK];
  const int tid = threadIdx.x;
  const int wave = tid >> 6, lane = tid & 63;
  const int wr = wave >> 1, wc = wave & 1;
  const int srow = lane >> 2;
  const int scol = (lane & 3) * 8;
  const int K = DFE;

  const ushort* ae = act + (size_t)e * T_TOK * DFE;
  const ushort* a0 = ae + (size_t)(m0 + wave * 32 + srow) * K + scol;
  const ushort* a1 = a0 + (size_t)16 * K;
  const ushort* dqe = dq + (size_t)e * D_DIM * DFE;
  const ushort* b0 = dqe + (size_t)(n0 + wave * 32 + srow) * K + scol;
  const ushort* b1 = b0 + (size_t)16 * K;
  ushort* lA0 = &As[(wave * 32) * BK];  ushort* lA1 = &As[(wave * 32 + 16) * BK];
  ushort* lB0 = &Bs[(wave * 32) * BK];  ushort* lB1 = &Bs[(wave * 32 + 16) * BK];

  floatx4 acc[4][4];
#pragma unroll
  for (int i = 0; i < 4; ++i)
#pragma unroll
    for (int j = 0; j < 4; ++j) acc[i][j] = (floatx4)(0.f);

  const int kc = (lane >> 4) * 8;
  const int rb = lane & 15;

  for (int k0 = 0; k0 < K; k0 += BK) {
    gld16(a0 + k0, lA0); gld16(a1 + k0, lA1);
    gld16(b0 + k0, lB0); gld16(b1 + k0, lB1);
    __syncthreads();
    short8 af[4], bf[4];
#pragma unroll
    for (int mt = 0; mt < 4; ++mt)
      af[mt] = *(const short8*)&As[(wr * 64 + mt * 16 + rb) * BK + kc];
#pragma unroll
    for (int nt = 0; nt < 4; ++nt)
      bf[nt] = *(const short8*)&Bs[(wc * 64 + nt * 16 + rb) * BK + kc];
#pragma unroll
    for (int mt = 0; mt < 4; ++mt)
#pragma unroll
      for (int nt = 0; nt < 4; ++nt)
        acc[mt][nt] = __builtin_amdgcn_mfma_f32_16x16x32_bf16(af[mt], bf[nt], acc[mt][nt], 0, 0, 0);
    __syncthreads();
  }
#pragma unroll
  for (int mt = 0; mt < 4; ++mt)
#pragma unroll
    for (int nt = 0; nt < 4; ++nt) {
      const int col = n0 + wc * 64 + nt * 16 + (lane & 15);
      const float dsc = down_s[e * D_DIM + col];
#pragma unroll
      for (int r = 0; r < 4; ++r) {
        const int slot = m0 + wr * 64 + mt * 16 + (lane >> 4) * 4 + r;
        if (slot < ce) {
          const int t = tok_list[e * T_TOK + slot];
          const float coef = tok_coef[e * T_TOK + slot];
          atomicAdd(&out[(size_t)t * D_DIM + col], coef * acc[mt][nt][r] * dsc);
        }
      }
    }
}

// ---------------------------------------------------------------------------
extern "C" void kernel_launch(void* const* d_in, const int* in_sizes, int n_in,
                              void* d_out, int out_size, void* d_ws, size_t ws_size,
                              hipStream_t stream) {
  const float* x         = (const float*)d_in[0];
  const float* rw        = (const float*)d_in[1];
  const float* sh_gate_w = (const float*)d_in[2];
  const float* sh_up_w   = (const float*)d_in[3];
  const float* sh_down_w = (const float*)d_in[4];
  const float* gate_s    = (const float*)d_in[5];
  const float* up_s      = (const float*)d_in[6];
  const float* down_s    = (const float*)d_in[7];
  const float* alpha     = (const float*)d_in[8];
  const int*   gate_q    = (const int*)d_in[9];
  const int*   up_q      = (const int*)d_in[10];
  const int*   down_q    = (const int*)d_in[11];

  char* ws = (char*)d_ws;
  const size_t MB = 1u << 20;
  int*   cnt      = (int*)ws;
  int*   tok_list = (int*)(ws + 1024);
  float* tok_coef = (float*)(ws + 1024 + 65536);
  float* csum     = (float*)(ws + 1024 + 2 * 65536);
  ushort* xb      = (ushort*)(ws + 1 * MB);    // 4 MB  [2048,1024]
  ushort* sgb     = (ushort*)(ws + 5 * MB);    // 4 MB  [2048,1024]
  ushort* sub     = (ushort*)(ws + 9 * MB);    // 4 MB  [2048,1024]
  ushort* sbuf    = (ushort*)(ws + 13 * MB);   // 8 MB  [2048,2048]
  ushort* sdb     = (ushort*)(ws + 21 * MB);   // 4 MB  [1024,2048]
  ushort* gqb     = (ushort*)(ws + 25 * MB);   // 8 MB  [8,512,1024]
  ushort* uqb     = (ushort*)(ws + 33 * MB);   // 8 MB  [8,512,1024]
  ushort* dqb     = (ushort*)(ws + 41 * MB);   // 8 MB  [8,1024,512]
  // act aliases sgb..sbuf (16 MB), dead after mfma_shared_down
  ushort* act     = (ushort*)(ws + 5 * MB);    // [8,2048,512] bf16 = 16 MB

  float* out = (float*)d_out;

  hipMemsetAsync(cnt, 0, E_NUM * sizeof(int), stream);

  // conversions
  cvt_f32_bf16_multi<<<dim3(1024, 4), 256, 0, stream>>>(
      x, sh_gate_w, sh_up_w, sh_down_w, xb, sgb, sub, sdb);
  cvt_i32_bf16_multi<<<dim3(2048, 3), 256, 0, stream>>>(
      gate_q, up_q, down_q, gqb, uqb, dqb);

  router_kernel<<<T_TOK, 64, 0, stream>>>(x, rw, alpha, cnt, tok_list, tok_coef, csum);

  mfma_shared_gateup<<<dim3(DFS / BN, T_TOK / BM), 256, 0, stream>>>(xb, sgb, sub, sbuf);
  mfma_shared_down<<<dim3(D_DIM / BN, T_TOK / BM), 256, 0, stream>>>(sbuf, sdb, csum, out);
  mfma_expert_gateup<<<dim3(DFE / BN, T_TOK / BM, E_NUM), 256, 0, stream>>>(
      xb, gqb, uqb, gate_s, up_s, cnt, tok_list, act);
  mfma_expert_down<<<dim3(D_DIM / BN, T_TOK / BM, E_NUM), 256, 0, stream>>>(
      act, dqb, down_s, cnt, tok_list, tok_coef, out);
}

// Round 3
// 340.744 us; speedup vs baseline: 3.1815x; 1.0251x over previous
//
#include <hip/hip_runtime.h>
#include <math.h>

// Problem constants (from setup_inputs)
#define T_TOK 2048   // B*S
#define D_DIM 1024   // hidden
#define E_NUM 8      // experts
#define DFS   2048   // shared ffn
#define DFE   512    // expert ffn

#define BM 128
#define BN 128
#define BK 32

typedef short short8 __attribute__((ext_vector_type(8)));
typedef float floatx4 __attribute__((ext_vector_type(4)));
typedef unsigned short ushort;

// float -> bf16 (RNE)
__device__ __forceinline__ ushort f2b(float f) {
  union { float f; unsigned u; } v; v.f = f;
  unsigned r = (v.u + 0x7fffu + ((v.u >> 16) & 1u)) >> 16;
  return (ushort)r;
}

// async global->LDS, 16B per lane. lds ptr must be wave-uniform.
__device__ __forceinline__ void gld16(const ushort* g, ushort* l) {
  __builtin_amdgcn_global_load_lds(
      (const __attribute__((address_space(1))) void*)g,
      (__attribute__((address_space(3))) void*)l,
      16, 0, 0);
}

__device__ __forceinline__ float silu_mul(float g, float u) {
  return (g / (1.f + __expf(-g))) * u;
}

// ---------------------------------------------------------------------------
// Conversion: 3x fp32 arrays of 2M elements -> bf16.  grid (1024, 3) x 256.
// ---------------------------------------------------------------------------
__global__ __launch_bounds__(256) void cvt_f32_bf16_multi(
    const float* __restrict__ s0, const float* __restrict__ s1,
    const float* __restrict__ s2,
    ushort* __restrict__ d0, ushort* __restrict__ d1, ushort* __restrict__ d2) {
  const float* src; ushort* dst;
  switch (blockIdx.y) {
    case 0: src = s0; dst = d0; break;
    case 1: src = s1; dst = d1; break;
    default: src = s2; dst = d2; break;
  }
  size_t i = (size_t)blockIdx.x * 256 + threadIdx.x;   // 8 floats per thread
  const float4* sp = (const float4*)src;
  float4 a = sp[2 * i], b = sp[2 * i + 1];
  union { ushort u[8]; uint4 v; } o;
  o.u[0] = f2b(a.x); o.u[1] = f2b(a.y); o.u[2] = f2b(a.z); o.u[3] = f2b(a.w);
  o.u[4] = f2b(b.x); o.u[5] = f2b(b.y); o.u[6] = f2b(b.z); o.u[7] = f2b(b.w);
  ((uint4*)dst)[i] = o.v;
}

// 3x int32 arrays of 4M elements -> bf16 (exact for |v|<=128). grid (2048,3).
__global__ __launch_bounds__(256) void cvt_i32_bf16_multi(
    const int* __restrict__ s0, const int* __restrict__ s1,
    const int* __restrict__ s2,
    ushort* __restrict__ d0, ushort* __restrict__ d1, ushort* __restrict__ d2) {
  const int* src; ushort* dst;
  switch (blockIdx.y) {
    case 0: src = s0; dst = d0; break;
    case 1: src = s1; dst = d1; break;
    default: src = s2; dst = d2; break;
  }
  size_t i = (size_t)blockIdx.x * 256 + threadIdx.x;
  const int4* sp = (const int4*)src;
  int4 a = sp[2 * i], b = sp[2 * i + 1];
  union { ushort u[8]; uint4 v; } o;
  o.u[0] = f2b((float)a.x); o.u[1] = f2b((float)a.y);
  o.u[2] = f2b((float)a.z); o.u[3] = f2b((float)a.w);
  o.u[4] = f2b((float)b.x); o.u[5] = f2b((float)b.y);
  o.u[6] = f2b((float)b.z); o.u[7] = f2b((float)b.w);
  ((uint4*)dst)[i] = o.v;
}

// ---------------------------------------------------------------------------
// Router: 256 threads = 4 waves = 4 tokens per block; grid 512.
// Coalesced x staging into LDS (+ fused fp32->bf16 x conversion).
// Lane (e=l>>3, sub=l&7): fp32 dot over 32 float4 chunks; shfl-reduce.
// ---------------------------------------------------------------------------
__global__ __launch_bounds__(256) void router_kernel(
    const float* __restrict__ x, const float* __restrict__ rw,
    const float* __restrict__ alpha,
    int* __restrict__ cnt, int* __restrict__ tok_list,
    float* __restrict__ tok_coef, float* __restrict__ csum,
    ushort* __restrict__ xb) {
  __shared__ float xs[4 * D_DIM];
  const int tid = threadIdx.x;
  const size_t base = (size_t)blockIdx.x * 4 * D_DIM;
  // stage 4 tokens of x -> LDS, emit bf16 copy
#pragma unroll
  for (int j = 0; j < 4; ++j) {
    const int idx = j * 1024 + tid * 4;
    float4 v = *(const float4*)(x + base + idx);
    *(float4*)&xs[idx] = v;
    union { ushort u[4]; uint2 p; } o;
    o.u[0] = f2b(v.x); o.u[1] = f2b(v.y); o.u[2] = f2b(v.z); o.u[3] = f2b(v.w);
    *(uint2*)(xb + base + idx) = o.p;
  }
  __syncthreads();
  const int w = tid >> 6, l = tid & 63;
  const int t = blockIdx.x * 4 + w;
  const int e = l >> 3, sub = l & 7;
  const float* wr = rw + e * D_DIM;
  float acc = 0.f;
#pragma unroll
  for (int k = 0; k < 32; ++k) {
    const int d = k * 32 + sub * 4;
    float4 xv = *(const float4*)&xs[w * D_DIM + d];
    float4 wv = *(const float4*)(wr + d);
    acc += xv.x * wv.x + xv.y * wv.y + xv.z * wv.z + xv.w * wv.w;
  }
  acc += __shfl_xor(acc, 1);
  acc += __shfl_xor(acc, 2);
  acc += __shfl_xor(acc, 4);     // lane e*8 holds logit[e]
  float lg[8];
#pragma unroll
  for (int i = 0; i < 8; ++i) lg[i] = __shfl(acc, i * 8);
  if (l == 0) {
    int i0 = 0; float v0 = lg[0];
#pragma unroll
    for (int i = 1; i < E_NUM; ++i) if (lg[i] > v0) { v0 = lg[i]; i0 = i; }
    int i1 = -1; float v1 = -1e30f;
#pragma unroll
    for (int i = 0; i < E_NUM; ++i) {
      if (i == i0) continue;
      if (lg[i] > v1) { v1 = lg[i]; i1 = i; }
    }
    float w0 = 1.f / (1.f + __expf(v1 - v0));
    float w1 = 1.f - w0;
    float c0 = w0 * alpha[i0];
    float c1 = w1 * alpha[i1];
    csum[t] = c0 + c1;
    int p0 = atomicAdd(&cnt[i0], 1);
    tok_list[i0 * T_TOK + p0] = t; tok_coef[i0 * T_TOK + p0] = c0;
    int p1 = atomicAdd(&cnt[i1], 1);
    tok_list[i1 * T_TOK + p1] = t; tok_coef[i1 * T_TOK + p1] = c1;
  }
}

// ---------------------------------------------------------------------------
// MFMA GEMM kernels.  128x128 tile, BK=32, 4 waves, each wave 64x64.
// A [M,K] bf16 row-major; B [N,K] bf16 row-major (i.e. B^T GEMM).
// ---------------------------------------------------------------------------

// Shared gate+up fused:  s = silu(x@Wg^T) * (x@Wu^T), bf16 out [T, DFS]
__global__ __launch_bounds__(256) void mfma_shared_gateup(
    const ushort* __restrict__ xb, const ushort* __restrict__ wg,
    const ushort* __restrict__ wu, ushort* __restrict__ sbuf) {
  __shared__ ushort As[BM * BK];
  __shared__ ushort Bg[BN * BK];
  __shared__ ushort Bu[BN * BK];
  const int tid = threadIdx.x;
  const int wave = tid >> 6, lane = tid & 63;
  const int wr = wave >> 1, wc = wave & 1;
  const int m0 = blockIdx.y * BM, n0 = blockIdx.x * BN;
  const int srow = lane >> 2;           // 0..15
  const int scol = (lane & 3) * 8;      // element offset within 32-elem row
  const int K = D_DIM;

  const ushort* a0 = xb + (size_t)(m0 + wave * 32 + srow) * K + scol;
  const ushort* a1 = a0 + (size_t)16 * K;
  const ushort* g0 = wg + (size_t)(n0 + wave * 32 + srow) * K + scol;
  const ushort* g1 = g0 + (size_t)16 * K;
  const ushort* u0 = wu + (size_t)(n0 + wave * 32 + srow) * K + scol;
  const ushort* u1 = u0 + (size_t)16 * K;
  ushort* lA0 = &As[(wave * 32) * BK];      ushort* lA1 = &As[(wave * 32 + 16) * BK];
  ushort* lG0 = &Bg[(wave * 32) * BK];      ushort* lG1 = &Bg[(wave * 32 + 16) * BK];
  ushort* lU0 = &Bu[(wave * 32) * BK];      ushort* lU1 = &Bu[(wave * 32 + 16) * BK];

  floatx4 accg[4][4], accu[4][4];
#pragma unroll
  for (int i = 0; i < 4; ++i)
#pragma unroll
    for (int j = 0; j < 4; ++j) { accg[i][j] = (floatx4)(0.f); accu[i][j] = (floatx4)(0.f); }

  const int kc = (lane >> 4) * 8;
  const int rb = lane & 15;

  for (int k0 = 0; k0 < K; k0 += BK) {
    gld16(a0 + k0, lA0); gld16(a1 + k0, lA1);
    gld16(g0 + k0, lG0); gld16(g1 + k0, lG1);
    gld16(u0 + k0, lU0); gld16(u1 + k0, lU1);
    __syncthreads();
    short8 af[4], gf[4], uf[4];
#pragma unroll
    for (int mt = 0; mt < 4; ++mt)
      af[mt] = *(const short8*)&As[(wr * 64 + mt * 16 + rb) * BK + kc];
#pragma unroll
    for (int nt = 0; nt < 4; ++nt) {
      gf[nt] = *(const short8*)&Bg[(wc * 64 + nt * 16 + rb) * BK + kc];
      uf[nt] = *(const short8*)&Bu[(wc * 64 + nt * 16 + rb) * BK + kc];
    }
#pragma unroll
    for (int mt = 0; mt < 4; ++mt)
#pragma unroll
      for (int nt = 0; nt < 4; ++nt) {
        accg[mt][nt] = __builtin_amdgcn_mfma_f32_16x16x32_bf16(af[mt], gf[nt], accg[mt][nt], 0, 0, 0);
        accu[mt][nt] = __builtin_amdgcn_mfma_f32_16x16x32_bf16(af[mt], uf[nt], accu[mt][nt], 0, 0, 0);
      }
    __syncthreads();
  }
  // epilogue: silu(g)*u -> bf16
#pragma unroll
  for (int mt = 0; mt < 4; ++mt)
#pragma unroll
    for (int nt = 0; nt < 4; ++nt) {
      const int col = n0 + wc * 64 + nt * 16 + (lane & 15);
#pragma unroll
      for (int r = 0; r < 4; ++r) {
        const int row = m0 + wr * 64 + mt * 16 + (lane >> 4) * 4 + r;
        float s = silu_mul(accg[mt][nt][r], accu[mt][nt][r]);
        sbuf[(size_t)row * DFS + col] = f2b(s);
      }
    }
}

// Shared down:  out[t,d] = (1-csum[t]) * (s @ Wd^T)
__global__ __launch_bounds__(256) void mfma_shared_down(
    const ushort* __restrict__ sb, const ushort* __restrict__ wd,
    const float* __restrict__ csum, float* __restrict__ out) {
  __shared__ ushort As[BM * BK];
  __shared__ ushort Bs[BN * BK];
  const int tid = threadIdx.x;
  const int wave = tid >> 6, lane = tid & 63;
  const int wr = wave >> 1, wc = wave & 1;
  const int m0 = blockIdx.y * BM, n0 = blockIdx.x * BN;
  const int srow = lane >> 2;
  const int scol = (lane & 3) * 8;
  const int K = DFS;

  const ushort* a0 = sb + (size_t)(m0 + wave * 32 + srow) * K + scol;
  const ushort* a1 = a0 + (size_t)16 * K;
  const ushort* b0 = wd + (size_t)(n0 + wave * 32 + srow) * K + scol;
  const ushort* b1 = b0 + (size_t)16 * K;
  ushort* lA0 = &As[(wave * 32) * BK];  ushort* lA1 = &As[(wave * 32 + 16) * BK];
  ushort* lB0 = &Bs[(wave * 32) * BK];  ushort* lB1 = &Bs[(wave * 32 + 16) * BK];

  floatx4 acc[4][4];
#pragma unroll
  for (int i = 0; i < 4; ++i)
#pragma unroll
    for (int j = 0; j < 4; ++j) acc[i][j] = (floatx4)(0.f);

  const int kc = (lane >> 4) * 8;
  const int rb = lane & 15;

  for (int k0 = 0; k0 < K; k0 += BK) {
    gld16(a0 + k0, lA0); gld16(a1 + k0, lA1);
    gld16(b0 + k0, lB0); gld16(b1 + k0, lB1);
    __syncthreads();
    short8 af[4], bf[4];
#pragma unroll
    for (int mt = 0; mt < 4; ++mt)
      af[mt] = *(const short8*)&As[(wr * 64 + mt * 16 + rb) * BK + kc];
#pragma unroll
    for (int nt = 0; nt < 4; ++nt)
      bf[nt] = *(const short8*)&Bs[(wc * 64 + nt * 16 + rb) * BK + kc];
#pragma unroll
    for (int mt = 0; mt < 4; ++mt)
#pragma unroll
      for (int nt = 0; nt < 4; ++nt)
        acc[mt][nt] = __builtin_amdgcn_mfma_f32_16x16x32_bf16(af[mt], bf[nt], acc[mt][nt], 0, 0, 0);
    __syncthreads();
  }
#pragma unroll
  for (int mt = 0; mt < 4; ++mt)
#pragma unroll
    for (int nt = 0; nt < 4; ++nt) {
      const int col = n0 + wc * 64 + nt * 16 + (lane & 15);
#pragma unroll
      for (int r = 0; r < 4; ++r) {
        const int row = m0 + wr * 64 + mt * 16 + (lane >> 4) * 4 + r;
        out[(size_t)row * D_DIM + col] = (1.f - csum[row]) * acc[mt][nt][r];
      }
    }
}

// Expert gate+up (gathered rows):  act[e,slot,f] = silu(g*gs)* (u*us), bf16
__global__ __launch_bounds__(256) void mfma_expert_gateup(
    const ushort* __restrict__ xb, const ushort* __restrict__ gq,
    const ushort* __restrict__ uq, const float* __restrict__ gate_s,
    const float* __restrict__ up_s, const int* __restrict__ cnt,
    const int* __restrict__ tok_list, ushort* __restrict__ act) {
  const int e = blockIdx.z;
  const int ce = cnt[e];
  const int m0 = blockIdx.y * BM;
  if (m0 >= ce) return;
  const int n0 = blockIdx.x * BN;
  __shared__ ushort As[BM * BK];
  __shared__ ushort Bg[BN * BK];
  __shared__ ushort Bu[BN * BK];
  const int tid = threadIdx.x;
  const int wave = tid >> 6, lane = tid & 63;
  const int wr = wave >> 1, wc = wave & 1;
  const int srow = lane >> 2;
  const int scol = (lane & 3) * 8;
  const int K = D_DIM;

  const int r0 = m0 + wave * 32 + srow;
  const int r1 = r0 + 16;
  const int tk0 = (r0 < ce) ? tok_list[e * T_TOK + r0] : 0;
  const int tk1 = (r1 < ce) ? tok_list[e * T_TOK + r1] : 0;
  const ushort* a0 = xb + (size_t)tk0 * K + scol;
  const ushort* a1 = xb + (size_t)tk1 * K + scol;
  const ushort* gqe = gq + (size_t)e * DFE * D_DIM;
  const ushort* uqe = uq + (size_t)e * DFE * D_DIM;
  const ushort* g0 = gqe + (size_t)(n0 + wave * 32 + srow) * K + scol;
  const ushort* g1 = g0 + (size_t)16 * K;
  const ushort* u0 = uqe + (size_t)(n0 + wave * 32 + srow) * K + scol;
  const ushort* u1 = u0 + (size_t)16 * K;
  ushort* lA0 = &As[(wave * 32) * BK];  ushort* lA1 = &As[(wave * 32 + 16) * BK];
  ushort* lG0 = &Bg[(wave * 32) * BK];  ushort* lG1 = &Bg[(wave * 32 + 16) * BK];
  ushort* lU0 = &Bu[(wave * 32) * BK];  ushort* lU1 = &Bu[(wave * 32 + 16) * BK];

  floatx4 accg[4][4], accu[4][4];
#pragma unroll
  for (int i = 0; i < 4; ++i)
#pragma unroll
    for (int j = 0; j < 4; ++j) { accg[i][j] = (floatx4)(0.f); accu[i][j] = (floatx4)(0.f); }

  const int kc = (lane >> 4) * 8;
  const int rb = lane & 15;

  for (int k0 = 0; k0 < K; k0 += BK) {
    gld16(a0 + k0, lA0); gld16(a1 + k0, lA1);
    gld16(g0 + k0, lG0); gld16(g1 + k0, lG1);
    gld16(u0 + k0, lU0); gld16(u1 + k0, lU1);
    __syncthreads();
    short8 af[4], gf[4], uf[4];
#pragma unroll
    for (int mt = 0; mt < 4; ++mt)
      af[mt] = *(const short8*)&As[(wr * 64 + mt * 16 + rb) * BK + kc];
#pragma unroll
    for (int nt = 0; nt < 4; ++nt) {
      gf[nt] = *(const short8*)&Bg[(wc * 64 + nt * 16 + rb) * BK + kc];
      uf[nt] = *(const short8*)&Bu[(wc * 64 + nt * 16 + rb) * BK + kc];
    }
#pragma unroll
    for (int mt = 0; mt < 4; ++mt)
#pragma unroll
      for (int nt = 0; nt < 4; ++nt) {
        accg[mt][nt] = __builtin_amdgcn_mfma_f32_16x16x32_bf16(af[mt], gf[nt], accg[mt][nt], 0, 0, 0);
        accu[mt][nt] = __builtin_amdgcn_mfma_f32_16x16x32_bf16(af[mt], uf[nt], accu[mt][nt], 0, 0, 0);
      }
    __syncthreads();
  }
#pragma unroll
  for (int mt = 0; mt < 4; ++mt)
#pragma unroll
    for (int nt = 0; nt < 4; ++nt) {
      const int col = n0 + wc * 64 + nt * 16 + (lane & 15);
      const float gsc = gate_s[e * DFE + col];
      const float usc = up_s[e * DFE + col];
#pragma unroll
      for (int r = 0; r < 4; ++r) {
        const int slot = m0 + wr * 64 + mt * 16 + (lane >> 4) * 4 + r;
        float s = silu_mul(accg[mt][nt][r] * gsc, accu[mt][nt][r] * usc);
        act[((size_t)e * T_TOK + slot) * DFE + col] = f2b(s);
      }
    }
}

// Expert down:  out[tok,d] += coef * (act @ Wd^T) * down_s[d]   (atomic)
__global__ __launch_bounds__(256) void mfma_expert_down(
    const ushort* __restrict__ act, const ushort* __restrict__ dq,
    const float* __restrict__ down_s, const int* __restrict__ cnt,
    const int* __restrict__ tok_list, const float* __restrict__ tok_coef,
    float* __restrict__ out) {
  const int e = blockIdx.z;
  const int ce = cnt[e];
  const int m0 = blockIdx.y * BM;
  if (m0 >= ce) return;
  const int n0 = blockIdx.x * BN;
  __shared__ ushort As[BM * BK];
  __shared__ ushort Bs[BN * BK];
  const int tid = threadIdx.x;
  const int wave = tid >> 6, lane = tid & 63;
  const int wr = wave >> 1, wc = wave & 1;
  const int m0_ = m0;
  const int srow = lane >> 2;
  const int scol = (lane & 3) * 8;
  const int K = DFE;

  const ushort* ae = act + (size_t)e * T_TOK * DFE;
  const ushort* a0 = ae + (size_t)(m0_ + wave * 32 + srow) * K + scol;
  const ushort* a1 = a0 + (size_t)16 * K;
  const ushort* dqe = dq + (size_t)e * D_DIM * DFE;
  const ushort* b0 = dqe + (size_t)(n0 + wave * 32 + srow) * K + scol;
  const ushort* b1 = b0 + (size_t)16 * K;
  ushort* lA0 = &As[(wave * 32) * BK];  ushort* lA1 = &As[(wave * 32 + 16) * BK];
  ushort* lB0 = &Bs[(wave * 32) * BK];  ushort* lB1 = &Bs[(wave * 32 + 16) * BK];

  floatx4 acc[4][4];
#pragma unroll
  for (int i = 0; i < 4; ++i)
#pragma unroll
    for (int j = 0; j < 4; ++j) acc[i][j] = (floatx4)(0.f);

  const int kc = (lane >> 4) * 8;
  const int rb = lane & 15;

  for (int k0 = 0; k0 < K; k0 += BK) {
    gld16(a0 + k0, lA0); gld16(a1 + k0, lA1);
    gld16(b0 + k0, lB0); gld16(b1 + k0, lB1);
    __syncthreads();
    short8 af[4], bf[4];
#pragma unroll
    for (int mt = 0; mt < 4; ++mt)
      af[mt] = *(const short8*)&As[(wr * 64 + mt * 16 + rb) * BK + kc];
#pragma unroll
    for (int nt = 0; nt < 4; ++nt)
      bf[nt] = *(const short8*)&Bs[(wc * 64 + nt * 16 + rb) * BK + kc];
#pragma unroll
    for (int mt = 0; mt < 4; ++mt)
#pragma unroll
      for (int nt = 0; nt < 4; ++nt)
        acc[mt][nt] = __builtin_amdgcn_mfma_f32_16x16x32_bf16(af[mt], bf[nt], acc[mt][nt], 0, 0, 0);
    __syncthreads();
  }
#pragma unroll
  for (int mt = 0; mt < 4; ++mt)
#pragma unroll
    for (int nt = 0; nt < 4; ++nt) {
      const int col = n0 + wc * 64 + nt * 16 + (lane & 15);
      const float dsc = down_s[e * D_DIM + col];
#pragma unroll
      for (int r = 0; r < 4; ++r) {
        const int slot = m0 + wr * 64 + mt * 16 + (lane >> 4) * 4 + r;
        if (slot < ce) {
          const int t = tok_list[e * T_TOK + slot];
          const float coef = tok_coef[e * T_TOK + slot];
          atomicAdd(&out[(size_t)t * D_DIM + col], coef * acc[mt][nt][r] * dsc);
        }
      }
    }
}

// ---------------------------------------------------------------------------
extern "C" void kernel_launch(void* const* d_in, const int* in_sizes, int n_in,
                              void* d_out, int out_size, void* d_ws, size_t ws_size,
                              hipStream_t stream) {
  const float* x         = (const float*)d_in[0];
  const float* rw        = (const float*)d_in[1];
  const float* sh_gate_w = (const float*)d_in[2];
  const float* sh_up_w   = (const float*)d_in[3];
  const float* sh_down_w = (const float*)d_in[4];
  const float* gate_s    = (const float*)d_in[5];
  const float* up_s      = (const float*)d_in[6];
  const float* down_s    = (const float*)d_in[7];
  const float* alpha     = (const float*)d_in[8];
  const int*   gate_q    = (const int*)d_in[9];
  const int*   up_q      = (const int*)d_in[10];
  const int*   down_q    = (const int*)d_in[11];

  char* ws = (char*)d_ws;
  const size_t MB = 1u << 20;
  int*   cnt      = (int*)ws;
  int*   tok_list = (int*)(ws + 1024);
  float* tok_coef = (float*)(ws + 1024 + 65536);
  float* csum     = (float*)(ws + 1024 + 2 * 65536);
  ushort* xb      = (ushort*)(ws + 1 * MB);    // 4 MB  [2048,1024]
  ushort* sgb     = (ushort*)(ws + 5 * MB);    // 4 MB  [2048,1024]
  ushort* sub     = (ushort*)(ws + 9 * MB);    // 4 MB  [2048,1024]
  ushort* sbuf    = (ushort*)(ws + 13 * MB);   // 8 MB  [2048,2048]
  ushort* sdb     = (ushort*)(ws + 21 * MB);   // 4 MB  [1024,2048]
  ushort* gqb     = (ushort*)(ws + 25 * MB);   // 8 MB  [8,512,1024]
  ushort* uqb     = (ushort*)(ws + 33 * MB);   // 8 MB  [8,512,1024]
  ushort* dqb     = (ushort*)(ws + 41 * MB);   // 8 MB  [8,1024,512]
  // act aliases sgb..sbuf (16 MB), dead after mfma_shared_down
  ushort* act     = (ushort*)(ws + 5 * MB);    // [8,2048,512] bf16 = 16 MB

  float* out = (float*)d_out;

  hipMemsetAsync(cnt, 0, E_NUM * sizeof(int), stream);

  router_kernel<<<512, 256, 0, stream>>>(x, rw, alpha, cnt, tok_list, tok_coef, csum, xb);
  cvt_f32_bf16_multi<<<dim3(1024, 3), 256, 0, stream>>>(
      sh_gate_w, sh_up_w, sh_down_w, sgb, sub, sdb);
  cvt_i32_bf16_multi<<<dim3(2048, 3), 256, 0, stream>>>(
      gate_q, up_q, down_q, gqb, uqb, dqb);

  mfma_shared_gateup<<<dim3(DFS / BN, T_TOK / BM), 256, 0, stream>>>(xb, sgb, sub, sbuf);
  mfma_shared_down<<<dim3(D_DIM / BN, T_TOK / BM), 256, 0, stream>>>(sbuf, sdb, csum, out);
  mfma_expert_gateup<<<dim3(DFE / BN, T_TOK / BM, E_NUM), 256, 0, stream>>>(
      xb, gqb, uqb, gate_s, up_s, cnt, tok_list, act);
  mfma_expert_down<<<dim3(D_DIM / BN, T_TOK / BM, E_NUM), 256, 0, stream>>>(
      act, dqb, down_s, cnt, tok_list, tok_coef, out);
}

// Round 4
// 301.916 us; speedup vs baseline: 3.5907x; 1.1286x over previous
//
#include <hip/hip_runtime.h>
#include <math.h>

// Problem constants (from setup_inputs)
#define T_TOK 2048   // B*S
#define D_DIM 1024   // hidden
#define E_NUM 8      // experts
#define DFS   2048   // shared ffn
#define DFE   512    // expert ffn

#define BM 128
#define BN 128
#define BK 32

typedef short short8 __attribute__((ext_vector_type(8)));
typedef float floatx4 __attribute__((ext_vector_type(4)));
typedef unsigned short ushort;

// float -> bf16 (RNE)
__device__ __forceinline__ ushort f2b(float f) {
  union { float f; unsigned u; } v; v.f = f;
  unsigned r = (v.u + 0x7fffu + ((v.u >> 16) & 1u)) >> 16;
  return (ushort)r;
}

// async global->LDS, 16B per lane. lds ptr must be wave-uniform.
__device__ __forceinline__ void gld16(const ushort* g, ushort* l) {
  __builtin_amdgcn_global_load_lds(
      (const __attribute__((address_space(1))) void*)g,
      (__attribute__((address_space(3))) void*)l,
      16, 0, 0);
}

__device__ __forceinline__ float silu_mul(float g, float u) {
  return (g / (1.f + __expf(-g))) * u;
}

// ---------------------------------------------------------------------------
// Conversion: 3x fp32 arrays of 2M elements -> bf16.  grid (1024, 3) x 256.
// ---------------------------------------------------------------------------
__global__ __launch_bounds__(256) void cvt_f32_bf16_multi(
    const float* __restrict__ s0, const float* __restrict__ s1,
    const float* __restrict__ s2,
    ushort* __restrict__ d0, ushort* __restrict__ d1, ushort* __restrict__ d2) {
  const float* src; ushort* dst;
  switch (blockIdx.y) {
    case 0: src = s0; dst = d0; break;
    case 1: src = s1; dst = d1; break;
    default: src = s2; dst = d2; break;
  }
  size_t i = (size_t)blockIdx.x * 256 + threadIdx.x;   // 8 floats per thread
  const float4* sp = (const float4*)src;
  float4 a = sp[2 * i], b = sp[2 * i + 1];
  union { ushort u[8]; uint4 v; } o;
  o.u[0] = f2b(a.x); o.u[1] = f2b(a.y); o.u[2] = f2b(a.z); o.u[3] = f2b(a.w);
  o.u[4] = f2b(b.x); o.u[5] = f2b(b.y); o.u[6] = f2b(b.z); o.u[7] = f2b(b.w);
  ((uint4*)dst)[i] = o.v;
}

// 3x int32 arrays of 4M elements -> bf16 (exact for |v|<=128). grid (2048,3).
__global__ __launch_bounds__(256) void cvt_i32_bf16_multi(
    const int* __restrict__ s0, const int* __restrict__ s1,
    const int* __restrict__ s2,
    ushort* __restrict__ d0, ushort* __restrict__ d1, ushort* __restrict__ d2) {
  const int* src; ushort* dst;
  switch (blockIdx.y) {
    case 0: src = s0; dst = d0; break;
    case 1: src = s1; dst = d1; break;
    default: src = s2; dst = d2; break;
  }
  size_t i = (size_t)blockIdx.x * 256 + threadIdx.x;
  const int4* sp = (const int4*)src;
  int4 a = sp[2 * i], b = sp[2 * i + 1];
  union { ushort u[8]; uint4 v; } o;
  o.u[0] = f2b((float)a.x); o.u[1] = f2b((float)a.y);
  o.u[2] = f2b((float)a.z); o.u[3] = f2b((float)a.w);
  o.u[4] = f2b((float)b.x); o.u[5] = f2b((float)b.y);
  o.u[6] = f2b((float)b.z); o.u[7] = f2b((float)b.w);
  ((uint4*)dst)[i] = o.v;
}

// ---------------------------------------------------------------------------
// Router phase 1: 256 threads = 4 waves = 4 tokens per block; grid 512.
// Computes top-2 + softmax coefs per token; NO global atomics.
// Also emits bf16 copy of x.
// ---------------------------------------------------------------------------
__global__ __launch_bounds__(256) void router_logits(
    const float* __restrict__ x, const float* __restrict__ rw,
    const float* __restrict__ alpha,
    int* __restrict__ choice, float2* __restrict__ cpair,
    float* __restrict__ csum, ushort* __restrict__ xb) {
  __shared__ float xs[4 * D_DIM];
  const int tid = threadIdx.x;
  const size_t base = (size_t)blockIdx.x * 4 * D_DIM;
  // stage 4 tokens of x -> LDS, emit bf16 copy
#pragma unroll
  for (int j = 0; j < 4; ++j) {
    const int idx = j * 1024 + tid * 4;
    float4 v = *(const float4*)(x + base + idx);
    *(float4*)&xs[idx] = v;
    union { ushort u[4]; uint2 p; } o;
    o.u[0] = f2b(v.x); o.u[1] = f2b(v.y); o.u[2] = f2b(v.z); o.u[3] = f2b(v.w);
    *(uint2*)(xb + base + idx) = o.p;
  }
  __syncthreads();
  const int w = tid >> 6, l = tid & 63;
  const int t = blockIdx.x * 4 + w;
  const int e = l >> 3, sub = l & 7;
  const float* wr = rw + e * D_DIM;
  float acc = 0.f;
#pragma unroll
  for (int k = 0; k < 32; ++k) {
    const int d = k * 32 + sub * 4;
    float4 xv = *(const float4*)&xs[w * D_DIM + d];
    float4 wv = *(const float4*)(wr + d);
    acc += xv.x * wv.x + xv.y * wv.y + xv.z * wv.z + xv.w * wv.w;
  }
  acc += __shfl_xor(acc, 1);
  acc += __shfl_xor(acc, 2);
  acc += __shfl_xor(acc, 4);     // lane e*8 holds logit[e]
  float lg[8];
#pragma unroll
  for (int i = 0; i < 8; ++i) lg[i] = __shfl(acc, i * 8);
  if (l == 0) {
    int i0 = 0; float v0 = lg[0];
#pragma unroll
    for (int i = 1; i < E_NUM; ++i) if (lg[i] > v0) { v0 = lg[i]; i0 = i; }
    int i1 = -1; float v1 = -1e30f;
#pragma unroll
    for (int i = 0; i < E_NUM; ++i) {
      if (i == i0) continue;
      if (lg[i] > v1) { v1 = lg[i]; i1 = i; }
    }
    float w0 = 1.f / (1.f + __expf(v1 - v0));
    float w1 = 1.f - w0;
    float c0 = w0 * alpha[i0];
    float c1 = w1 * alpha[i1];
    csum[t] = c0 + c1;
    choice[t] = i0 | (i1 << 4);
    cpair[t] = make_float2(c0, c1);
  }
}

// ---------------------------------------------------------------------------
// Router phase 2: single block, LDS-atomic compaction into expert lists.
// ---------------------------------------------------------------------------
__global__ __launch_bounds__(1024) void build_lists(
    const int* __restrict__ choice, const float2* __restrict__ cpair,
    int* __restrict__ cnt, int* __restrict__ tok_list,
    float* __restrict__ tok_coef) {
  __shared__ int lcnt[E_NUM];
  const int tid = threadIdx.x;
  if (tid < E_NUM) lcnt[tid] = 0;
  __syncthreads();
#pragma unroll
  for (int r = 0; r < T_TOK / 1024; ++r) {
    const int t = r * 1024 + tid;
    const int ch = choice[t];
    const float2 c = cpair[t];
    const int i0 = ch & 15, i1 = ch >> 4;
    const int p0 = atomicAdd(&lcnt[i0], 1);
    tok_list[i0 * T_TOK + p0] = t; tok_coef[i0 * T_TOK + p0] = c.x;
    const int p1 = atomicAdd(&lcnt[i1], 1);
    tok_list[i1 * T_TOK + p1] = t; tok_coef[i1 * T_TOK + p1] = c.y;
  }
  __syncthreads();
  if (tid < E_NUM) cnt[tid] = lcnt[tid];
}

// ---------------------------------------------------------------------------
// MFMA GEMM kernels.  128x128 tile, BK=32, 4 waves, each wave 64x64.
// A [M,K] bf16 row-major; B [N,K] bf16 row-major (i.e. B^T GEMM).
// ---------------------------------------------------------------------------

// Shared gate+up fused:  s = silu(x@Wg^T) * (x@Wu^T), bf16 out [T, DFS]
__global__ __launch_bounds__(256) void mfma_shared_gateup(
    const ushort* __restrict__ xb, const ushort* __restrict__ wg,
    const ushort* __restrict__ wu, ushort* __restrict__ sbuf) {
  __shared__ ushort As[BM * BK];
  __shared__ ushort Bg[BN * BK];
  __shared__ ushort Bu[BN * BK];
  const int tid = threadIdx.x;
  const int wave = tid >> 6, lane = tid & 63;
  const int wr = wave >> 1, wc = wave & 1;
  const int m0 = blockIdx.y * BM, n0 = blockIdx.x * BN;
  const int srow = lane >> 2;           // 0..15
  const int scol = (lane & 3) * 8;      // element offset within 32-elem row
  const int K = D_DIM;

  const ushort* a0 = xb + (size_t)(m0 + wave * 32 + srow) * K + scol;
  const ushort* a1 = a0 + (size_t)16 * K;
  const ushort* g0 = wg + (size_t)(n0 + wave * 32 + srow) * K + scol;
  const ushort* g1 = g0 + (size_t)16 * K;
  const ushort* u0 = wu + (size_t)(n0 + wave * 32 + srow) * K + scol;
  const ushort* u1 = u0 + (size_t)16 * K;
  ushort* lA0 = &As[(wave * 32) * BK];      ushort* lA1 = &As[(wave * 32 + 16) * BK];
  ushort* lG0 = &Bg[(wave * 32) * BK];      ushort* lG1 = &Bg[(wave * 32 + 16) * BK];
  ushort* lU0 = &Bu[(wave * 32) * BK];      ushort* lU1 = &Bu[(wave * 32 + 16) * BK];

  floatx4 accg[4][4], accu[4][4];
#pragma unroll
  for (int i = 0; i < 4; ++i)
#pragma unroll
    for (int j = 0; j < 4; ++j) { accg[i][j] = (floatx4)(0.f); accu[i][j] = (floatx4)(0.f); }

  const int kc = (lane >> 4) * 8;
  const int rb = lane & 15;

  for (int k0 = 0; k0 < K; k0 += BK) {
    gld16(a0 + k0, lA0); gld16(a1 + k0, lA1);
    gld16(g0 + k0, lG0); gld16(g1 + k0, lG1);
    gld16(u0 + k0, lU0); gld16(u1 + k0, lU1);
    __syncthreads();
    short8 af[4], gf[4], uf[4];
#pragma unroll
    for (int mt = 0; mt < 4; ++mt)
      af[mt] = *(const short8*)&As[(wr * 64 + mt * 16 + rb) * BK + kc];
#pragma unroll
    for (int nt = 0; nt < 4; ++nt) {
      gf[nt] = *(const short8*)&Bg[(wc * 64 + nt * 16 + rb) * BK + kc];
      uf[nt] = *(const short8*)&Bu[(wc * 64 + nt * 16 + rb) * BK + kc];
    }
#pragma unroll
    for (int mt = 0; mt < 4; ++mt)
#pragma unroll
      for (int nt = 0; nt < 4; ++nt) {
        accg[mt][nt] = __builtin_amdgcn_mfma_f32_16x16x32_bf16(af[mt], gf[nt], accg[mt][nt], 0, 0, 0);
        accu[mt][nt] = __builtin_amdgcn_mfma_f32_16x16x32_bf16(af[mt], uf[nt], accu[mt][nt], 0, 0, 0);
      }
    __syncthreads();
  }
  // epilogue: silu(g)*u -> bf16
#pragma unroll
  for (int mt = 0; mt < 4; ++mt)
#pragma unroll
    for (int nt = 0; nt < 4; ++nt) {
      const int col = n0 + wc * 64 + nt * 16 + (lane & 15);
#pragma unroll
      for (int r = 0; r < 4; ++r) {
        const int row = m0 + wr * 64 + mt * 16 + (lane >> 4) * 4 + r;
        float s = silu_mul(accg[mt][nt][r], accu[mt][nt][r]);
        sbuf[(size_t)row * DFS + col] = f2b(s);
      }
    }
}

// Shared down:  out[t,d] = (1-csum[t]) * (s @ Wd^T)
__global__ __launch_bounds__(256) void mfma_shared_down(
    const ushort* __restrict__ sb, const ushort* __restrict__ wd,
    const float* __restrict__ csum, float* __restrict__ out) {
  __shared__ ushort As[BM * BK];
  __shared__ ushort Bs[BN * BK];
  const int tid = threadIdx.x;
  const int wave = tid >> 6, lane = tid & 63;
  const int wr = wave >> 1, wc = wave & 1;
  const int m0 = blockIdx.y * BM, n0 = blockIdx.x * BN;
  const int srow = lane >> 2;
  const int scol = (lane & 3) * 8;
  const int K = DFS;

  const ushort* a0 = sb + (size_t)(m0 + wave * 32 + srow) * K + scol;
  const ushort* a1 = a0 + (size_t)16 * K;
  const ushort* b0 = wd + (size_t)(n0 + wave * 32 + srow) * K + scol;
  const ushort* b1 = b0 + (size_t)16 * K;
  ushort* lA0 = &As[(wave * 32) * BK];  ushort* lA1 = &As[(wave * 32 + 16) * BK];
  ushort* lB0 = &Bs[(wave * 32) * BK];  ushort* lB1 = &Bs[(wave * 32 + 16) * BK];

  floatx4 acc[4][4];
#pragma unroll
  for (int i = 0; i < 4; ++i)
#pragma unroll
    for (int j = 0; j < 4; ++j) acc[i][j] = (floatx4)(0.f);

  const int kc = (lane >> 4) * 8;
  const int rb = lane & 15;

  for (int k0 = 0; k0 < K; k0 += BK) {
    gld16(a0 + k0, lA0); gld16(a1 + k0, lA1);
    gld16(b0 + k0, lB0); gld16(b1 + k0, lB1);
    __syncthreads();
    short8 af[4], bf[4];
#pragma unroll
    for (int mt = 0; mt < 4; ++mt)
      af[mt] = *(const short8*)&As[(wr * 64 + mt * 16 + rb) * BK + kc];
#pragma unroll
    for (int nt = 0; nt < 4; ++nt)
      bf[nt] = *(const short8*)&Bs[(wc * 64 + nt * 16 + rb) * BK + kc];
#pragma unroll
    for (int mt = 0; mt < 4; ++mt)
#pragma unroll
      for (int nt = 0; nt < 4; ++nt)
        acc[mt][nt] = __builtin_amdgcn_mfma_f32_16x16x32_bf16(af[mt], bf[nt], acc[mt][nt], 0, 0, 0);
    __syncthreads();
  }
#pragma unroll
  for (int mt = 0; mt < 4; ++mt)
#pragma unroll
    for (int nt = 0; nt < 4; ++nt) {
      const int col = n0 + wc * 64 + nt * 16 + (lane & 15);
#pragma unroll
      for (int r = 0; r < 4; ++r) {
        const int row = m0 + wr * 64 + mt * 16 + (lane >> 4) * 4 + r;
        out[(size_t)row * D_DIM + col] = (1.f - csum[row]) * acc[mt][nt][r];
      }
    }
}

// Expert gate+up (gathered rows):  act[e,slot,f] = silu(g*gs)* (u*us), bf16
__global__ __launch_bounds__(256) void mfma_expert_gateup(
    const ushort* __restrict__ xb, const ushort* __restrict__ gq,
    const ushort* __restrict__ uq, const float* __restrict__ gate_s,
    const float* __restrict__ up_s, const int* __restrict__ cnt,
    const int* __restrict__ tok_list, ushort* __restrict__ act) {
  const int e = blockIdx.z;
  const int ce = cnt[e];
  const int m0 = blockIdx.y * BM;
  if (m0 >= ce) return;
  const int n0 = blockIdx.x * BN;
  __shared__ ushort As[BM * BK];
  __shared__ ushort Bg[BN * BK];
  __shared__ ushort Bu[BN * BK];
  const int tid = threadIdx.x;
  const int wave = tid >> 6, lane = tid & 63;
  const int wr = wave >> 1, wc = wave & 1;
  const int srow = lane >> 2;
  const int scol = (lane & 3) * 8;
  const int K = D_DIM;

  const int r0 = m0 + wave * 32 + srow;
  const int r1 = r0 + 16;
  const int tk0 = (r0 < ce) ? tok_list[e * T_TOK + r0] : 0;
  const int tk1 = (r1 < ce) ? tok_list[e * T_TOK + r1] : 0;
  const ushort* a0 = xb + (size_t)tk0 * K + scol;
  const ushort* a1 = xb + (size_t)tk1 * K + scol;
  const ushort* gqe = gq + (size_t)e * DFE * D_DIM;
  const ushort* uqe = uq + (size_t)e * DFE * D_DIM;
  const ushort* g0 = gqe + (size_t)(n0 + wave * 32 + srow) * K + scol;
  const ushort* g1 = g0 + (size_t)16 * K;
  const ushort* u0 = uqe + (size_t)(n0 + wave * 32 + srow) * K + scol;
  const ushort* u1 = u0 + (size_t)16 * K;
  ushort* lA0 = &As[(wave * 32) * BK];  ushort* lA1 = &As[(wave * 32 + 16) * BK];
  ushort* lG0 = &Bg[(wave * 32) * BK];  ushort* lG1 = &Bg[(wave * 32 + 16) * BK];
  ushort* lU0 = &Bu[(wave * 32) * BK];  ushort* lU1 = &Bu[(wave * 32 + 16) * BK];

  floatx4 accg[4][4], accu[4][4];
#pragma unroll
  for (int i = 0; i < 4; ++i)
#pragma unroll
    for (int j = 0; j < 4; ++j) { accg[i][j] = (floatx4)(0.f); accu[i][j] = (floatx4)(0.f); }

  const int kc = (lane >> 4) * 8;
  const int rb = lane & 15;

  for (int k0 = 0; k0 < K; k0 += BK) {
    gld16(a0 + k0, lA0); gld16(a1 + k0, lA1);
    gld16(g0 + k0, lG0); gld16(g1 + k0, lG1);
    gld16(u0 + k0, lU0); gld16(u1 + k0, lU1);
    __syncthreads();
    short8 af[4], gf[4], uf[4];
#pragma unroll
    for (int mt = 0; mt < 4; ++mt)
      af[mt] = *(const short8*)&As[(wr * 64 + mt * 16 + rb) * BK + kc];
#pragma unroll
    for (int nt = 0; nt < 4; ++nt) {
      gf[nt] = *(const short8*)&Bg[(wc * 64 + nt * 16 + rb) * BK + kc];
      uf[nt] = *(const short8*)&Bu[(wc * 64 + nt * 16 + rb) * BK + kc];
    }
#pragma unroll
    for (int mt = 0; mt < 4; ++mt)
#pragma unroll
      for (int nt = 0; nt < 4; ++nt) {
        accg[mt][nt] = __builtin_amdgcn_mfma_f32_16x16x32_bf16(af[mt], gf[nt], accg[mt][nt], 0, 0, 0);
        accu[mt][nt] = __builtin_amdgcn_mfma_f32_16x16x32_bf16(af[mt], uf[nt], accu[mt][nt], 0, 0, 0);
      }
    __syncthreads();
  }
#pragma unroll
  for (int mt = 0; mt < 4; ++mt)
#pragma unroll
    for (int nt = 0; nt < 4; ++nt) {
      const int col = n0 + wc * 64 + nt * 16 + (lane & 15);
      const float gsc = gate_s[e * DFE + col];
      const float usc = up_s[e * DFE + col];
#pragma unroll
      for (int r = 0; r < 4; ++r) {
        const int slot = m0 + wr * 64 + mt * 16 + (lane >> 4) * 4 + r;
        float s = silu_mul(accg[mt][nt][r] * gsc, accu[mt][nt][r] * usc);
        act[((size_t)e * T_TOK + slot) * DFE + col] = f2b(s);
      }
    }
}

// Expert down:  out[tok,d] += coef * (act @ Wd^T) * down_s[d]   (atomic)
__global__ __launch_bounds__(256) void mfma_expert_down(
    const ushort* __restrict__ act, const ushort* __restrict__ dq,
    const float* __restrict__ down_s, const int* __restrict__ cnt,
    const int* __restrict__ tok_list, const float* __restrict__ tok_coef,
    float* __restrict__ out) {
  const int e = blockIdx.z;
  const int ce = cnt[e];
  const int m0 = blockIdx.y * BM;
  if (m0 >= ce) return;
  const int n0 = blockIdx.x * BN;
  __shared__ ushort As[BM * BK];
  __shared__ ushort Bs[BN * BK];
  const int tid = threadIdx.x;
  const int wave = tid >> 6, lane = tid & 63;
  const int wr = wave >> 1, wc = wave & 1;
  const int srow = lane >> 2;
  const int scol = (lane & 3) * 8;
  const int K = DFE;

  const ushort* ae = act + (size_t)e * T_TOK * DFE;
  const ushort* a0 = ae + (size_t)(m0 + wave * 32 + srow) * K + scol;
  const ushort* a1 = a0 + (size_t)16 * K;
  const ushort* dqe = dq + (size_t)e * D_DIM * DFE;
  const ushort* b0 = dqe + (size_t)(n0 + wave * 32 + srow) * K + scol;
  const ushort* b1 = b0 + (size_t)16 * K;
  ushort* lA0 = &As[(wave * 32) * BK];  ushort* lA1 = &As[(wave * 32 + 16) * BK];
  ushort* lB0 = &Bs[(wave * 32) * BK];  ushort* lB1 = &Bs[(wave * 32 + 16) * BK];

  floatx4 acc[4][4];
#pragma unroll
  for (int i = 0; i < 4; ++i)
#pragma unroll
    for (int j = 0; j < 4; ++j) acc[i][j] = (floatx4)(0.f);

  const int kc = (lane >> 4) * 8;
  const int rb = lane & 15;

  for (int k0 = 0; k0 < K; k0 += BK) {
    gld16(a0 + k0, lA0); gld16(a1 + k0, lA1);
    gld16(b0 + k0, lB0); gld16(b1 + k0, lB1);
    __syncthreads();
    short8 af[4], bf[4];
#pragma unroll
    for (int mt = 0; mt < 4; ++mt)
      af[mt] = *(const short8*)&As[(wr * 64 + mt * 16 + rb) * BK + kc];
#pragma unroll
    for (int nt = 0; nt < 4; ++nt)
      bf[nt] = *(const short8*)&Bs[(wc * 64 + nt * 16 + rb) * BK + kc];
#pragma unroll
    for (int mt = 0; mt < 4; ++mt)
#pragma unroll
      for (int nt = 0; nt < 4; ++nt)
        acc[mt][nt] = __builtin_amdgcn_mfma_f32_16x16x32_bf16(af[mt], bf[nt], acc[mt][nt], 0, 0, 0);
    __syncthreads();
  }
#pragma unroll
  for (int mt = 0; mt < 4; ++mt)
#pragma unroll
    for (int nt = 0; nt < 4; ++nt) {
      const int col = n0 + wc * 64 + nt * 16 + (lane & 15);
      const float dsc = down_s[e * D_DIM + col];
#pragma unroll
      for (int r = 0; r < 4; ++r) {
        const int slot = m0 + wr * 64 + mt * 16 + (lane >> 4) * 4 + r;
        if (slot < ce) {
          const int t = tok_list[e * T_TOK + slot];
          const float coef = tok_coef[e * T_TOK + slot];
          atomicAdd(&out[(size_t)t * D_DIM + col], coef * acc[mt][nt][r] * dsc);
        }
      }
    }
}

// ---------------------------------------------------------------------------
extern "C" void kernel_launch(void* const* d_in, const int* in_sizes, int n_in,
                              void* d_out, int out_size, void* d_ws, size_t ws_size,
                              hipStream_t stream) {
  const float* x         = (const float*)d_in[0];
  const float* rw        = (const float*)d_in[1];
  const float* sh_gate_w = (const float*)d_in[2];
  const float* sh_up_w   = (const float*)d_in[3];
  const float* sh_down_w = (const float*)d_in[4];
  const float* gate_s    = (const float*)d_in[5];
  const float* up_s      = (const float*)d_in[6];
  const float* down_s    = (const float*)d_in[7];
  const float* alpha     = (const float*)d_in[8];
  const int*   gate_q    = (const int*)d_in[9];
  const int*   up_q      = (const int*)d_in[10];
  const int*   down_q    = (const int*)d_in[11];

  char* ws = (char*)d_ws;
  const size_t MB = 1u << 20;
  int*    cnt      = (int*)ws;                               // 32 B
  int*    tok_list = (int*)(ws + 1024);                      // 64 KB
  float*  tok_coef = (float*)(ws + 1024 + 65536);            // 64 KB
  float*  csum     = (float*)(ws + 1024 + 131072);           // 8 KB
  int*    choice   = (int*)(ws + 1024 + 139264);             // 8 KB
  float2* cpair    = (float2*)(ws + 1024 + 147456);          // 16 KB
  ushort* xb      = (ushort*)(ws + 1 * MB);    // 4 MB  [2048,1024]
  ushort* sgb     = (ushort*)(ws + 5 * MB);    // 4 MB  [2048,1024]
  ushort* sub     = (ushort*)(ws + 9 * MB);    // 4 MB  [2048,1024]
  ushort* sbuf    = (ushort*)(ws + 13 * MB);   // 8 MB  [2048,2048]
  ushort* sdb     = (ushort*)(ws + 21 * MB);   // 4 MB  [1024,2048]
  ushort* gqb     = (ushort*)(ws + 25 * MB);   // 8 MB  [8,512,1024]
  ushort* uqb     = (ushort*)(ws + 33 * MB);   // 8 MB  [8,512,1024]
  ushort* dqb     = (ushort*)(ws + 41 * MB);   // 8 MB  [8,1024,512]
  // act aliases sgb..sbuf (16 MB), dead after mfma_shared_down
  ushort* act     = (ushort*)(ws + 5 * MB);    // [8,2048,512] bf16 = 16 MB

  float* out = (float*)d_out;

  router_logits<<<512, 256, 0, stream>>>(x, rw, alpha, choice, cpair, csum, xb);
  build_lists<<<1, 1024, 0, stream>>>(choice, cpair, cnt, tok_list, tok_coef);
  cvt_f32_bf16_multi<<<dim3(1024, 3), 256, 0, stream>>>(
      sh_gate_w, sh_up_w, sh_down_w, sgb, sub, sdb);
  cvt_i32_bf16_multi<<<dim3(2048, 3), 256, 0, stream>>>(
      gate_q, up_q, down_q, gqb, uqb, dqb);

  mfma_shared_gateup<<<dim3(DFS / BN, T_TOK / BM), 256, 0, stream>>>(xb, sgb, sub, sbuf);
  mfma_shared_down<<<dim3(D_DIM / BN, T_TOK / BM), 256, 0, stream>>>(sbuf, sdb, csum, out);
  mfma_expert_gateup<<<dim3(DFE / BN, T_TOK / BM, E_NUM), 256, 0, stream>>>(
      xb, gqb, uqb, gate_s, up_s, cnt, tok_list, act);
  mfma_expert_down<<<dim3(D_DIM / BN, T_TOK / BM, E_NUM), 256, 0, stream>>>(
      act, dqb, down_s, cnt, tok_list, tok_coef, out);
}